// Round 12
// baseline (138.975 us; speedup 1.0000x reference)
//
#include <hip/hip_runtime.h>

// IM2HT Hough voting:
//   out[b,c,ht] = sum_{n: ht_idx[n]==ht} input_im[b,c,im_idx[n]] * weight[n]
// B*C = 128, HW = 16384, NHT = 184*180 = 33120, N = 1.5M votes.
//
// Pipeline (memset + 2 kernels):
//   0. hipMemsetAsync : zero bucket cursors + overflow counter (contiguous)
//   1. k_work   : blocks 0..366  -> bucket multi-split (1024 thr x 4 votes,
//                                   552 coarse ranges, private chunks)
//                 blocks 367..878 -> transpose in[BC][HW] -> xTh[HW][128] bf16
//                 (disjoint work, no inter-dependence; transpose hides under
//                  the longer bucket phase)
//   2. k_accum8 : one 1024-thr block per range (16 waves):
//                 LDS-stage records -> in-LDS counting sort by fine bin (padded
//                 to x4) -> ALL 16 waves accumulate bins strided (bin=w,w+16,..)
//                 via quarter-wave bf16x8 gathers (1 gather instr per 4 votes,
//                 L2-resident) -> lacc[60][129] overlaid on staging buf ->
//                 fused transposed write out[ch][r*60+j] (+ overflow fold-in)

#define HW   16384
#define BC   128
#define NHT  33120
#define RB   60            // ht bins per coarse range
#define NB   552           // NHT / RB
#define CAPB 3712          // bkt slots per range (mean 2717)
#define CAPR 3528          // raw record clamp, +15 sigma
#define CAPD 3712          // sorted slots (<= 3528 + 3*60 = 3708)
#define VPB  4096          // votes per bucket block
#define NBK  367           // bucket blocks = ceil(N / VPB)
#define NTR  512           // transpose blocks (4 tiles each = 2048 tiles)
#define OFL_CAP 8192

typedef int iv4 __attribute__((ext_vector_type(4)));

__device__ __forceinline__ unsigned short f2bf(float f) {
  unsigned int u = __float_as_uint(f);
  u = (u + 0x7fff + ((u >> 16) & 1)) >> 16;   // round-to-nearest-even
  return (unsigned short)u;
}

// blocks 0..NBK-1: bucket pass; blocks NBK..NBK+NTR-1: transpose pass
__global__ __launch_bounds__(1024) void k_work(
    const float* __restrict__ in, unsigned short* __restrict__ xTh,
    const int* __restrict__ im, const int* __restrict__ ht,
    const float* __restrict__ wt, int n,
    int* __restrict__ gcur, int2* __restrict__ bkt,
    int* __restrict__ ofl_cnt, int2* __restrict__ ofl) {
  __shared__ __align__(16) char smem[4 * 32 * 33 * 4];  // 16,896 B union
  int tid = threadIdx.x;

  if (blockIdx.x >= NBK) {
    // ---- transpose: 4 independent 32x32 tiles per block ----
    float* tilef = (float*)smem;
    int sub = tid >> 8;                  // 0..3
    int t256 = tid & 255;
    int tx = t256 & 31, ty = t256 >> 5;  // 32 x 8
    int tileIdx = (blockIdx.x - NBK) * 4 + sub;
    int hw0 = (tileIdx & 511) * 32, bc0 = (tileIdx >> 9) * 32;
    float* tile = tilef + sub * (32 * 33);
#pragma unroll
    for (int k = 0; k < 32; k += 8)
      tile[(ty + k) * 33 + tx] = in[(size_t)(bc0 + ty + k) * HW + hw0 + tx];
    __syncthreads();
#pragma unroll
    for (int k = 0; k < 32; k += 8)
      xTh[(size_t)(hw0 + ty + k) * BC + bc0 + tx] = f2bf(tile[tx * 33 + ty + k]);
    return;
  }

  // ---- bucket multi-split ----
  int* cnt = (int*)smem;          // [NB]
  int* base = cnt + NB;           // [NB]
  int i0 = blockIdx.x * VPB;
  for (int b = tid; b < NB; b += 1024) cnt[b] = 0;
  __syncthreads();
  int hv[4];
#pragma unroll
  for (int k = 0; k < 4; ++k) {
    int i = i0 + k * 1024 + tid;
    hv[k] = (i < n) ? ht[i] : -1;
    if (i < n) atomicAdd(&cnt[hv[k] / RB], 1);
  }
  __syncthreads();
  for (int b = tid; b < NB; b += 1024) {
    int c = cnt[b];
    base[b] = c ? atomicAdd(&gcur[b], c) : 0;  // reserve private chunk
    cnt[b] = 0;                                 // reuse as local cursor
  }
  __syncthreads();
#pragma unroll
  for (int k = 0; k < 4; ++k) {
    int i = i0 + k * 1024 + tid;
    if (i < n) {
      int h = hv[k];
      int b = h / RB;
      int hl = h - b * RB;
      int pos = base[b] + atomicAdd(&cnt[b], 1);
      if (pos < CAPR) {
        bkt[(size_t)b * CAPB + pos] =
            make_int2((im[i] & 0x3FFF) | (hl << 14), __float_as_int(wt[i]));
      } else {
        int o = atomicAdd(ofl_cnt, 1);
        if (o < OFL_CAP)
          ofl[o] = make_int2((im[i] & 0x3FFF) | (h << 14), __float_as_int(wt[i]));
      }
    }
  }
}

// one block per range: LDS counting sort + quarter-wave gather accumulate
__global__ __launch_bounds__(1024) void k_accum8(
    const int2* __restrict__ bkt, const int* __restrict__ gcur,
    const unsigned short* __restrict__ xTh, float* __restrict__ out,
    const int* __restrict__ ofl_cnt, const int2* __restrict__ ofl) {
  __shared__ int2 sdst[CAPD];                  // 29,696 B sorted records
  __shared__ float lacc[RB * 129];             // 30,960 B; staging buf overlaid
  __shared__ int hist[RB], off[RB], pcnt[RB], cur[RB];
  int2* buf = (int2*)lacc;                     // dead before lacc writes begin
  int tid = threadIdx.x;
  int r = blockIdx.x;
  int ht0 = r * RB;
  int n = gcur[r];
  if (n > CAPR) n = CAPR;
  const int2* s = bkt + (size_t)r * CAPB;
  for (int i = tid; i < n; i += 1024) buf[i] = s[i];   // single global read
  if (tid < RB) hist[tid] = 0;
  __syncthreads();
  for (int i = tid; i < n; i += 1024)
    atomicAdd(&hist[buf[i].x >> 14], 1);
  __syncthreads();
  if (tid < 64) {                              // wave-0 shfl inclusive scan
    int v = (tid < RB) ? ((hist[tid] + 3) & ~3) : 0;
    int inc = v;
#pragma unroll
    for (int d = 1; d < 64; d <<= 1) {
      int t = __shfl_up(inc, d);
      if (tid >= d) inc += t;
    }
    if (tid < RB) { off[tid] = inc - v; pcnt[tid] = v; cur[tid] = 0; }
  }
  __syncthreads();
  if (tid < RB) {                              // weight-0 dummies in pad slots
    for (int d = hist[tid]; d < pcnt[tid]; ++d)
      sdst[off[tid] + d] = make_int2(0, 0);
  }
  for (int i = tid; i < n; i += 1024) {        // scatter into sorted order
    int2 v = buf[i];
    int hl = v.x >> 14;
    int pos = off[hl] + atomicAdd(&cur[hl], 1);
    sdst[pos] = make_int2(v.x & 0x3FFF, v.y);
  }
  __syncthreads();

  // accumulate: ALL 16 waves, bins strided; lane = (quarter q, octet cg)
  int w = __builtin_amdgcn_readfirstlane(tid >> 6);
  int lane = tid & 63;
  int q = lane >> 4;
  int cg = lane & 15;
  const unsigned short* xb = xTh + (cg << 3);
  for (int bin = w; bin < RB; bin += 16) {
    int o = off[bin], nb = pcnt[bin];          // nb % 4 == 0
    float acc[8] = {0, 0, 0, 0, 0, 0, 0, 0};

#define GATHER_FMA(IM, W)                                                     \
  {                                                                           \
    iv4 xd = *(const iv4*)(xb + ((size_t)(IM) << 7));                         \
    _Pragma("unroll") for (int c = 0; c < 4; ++c) {                           \
      float lo = __uint_as_float(((unsigned int)xd[c]) << 16);                \
      float hi = __uint_as_float(((unsigned int)xd[c]) & 0xffff0000u);        \
      acc[2 * c]     = fmaf((W), lo, acc[2 * c]);                             \
      acc[2 * c + 1] = fmaf((W), hi, acc[2 * c + 1]);                         \
    }                                                                         \
  }

    int i = 0;
    for (; i + 8 <= nb; i += 8) {              // 8 votes: 2 broadcast ds_reads + 2 gathers
      int2 r0 = sdst[o + i + q];
      int2 r1 = sdst[o + i + 4 + q];
      GATHER_FMA(r0.x, __int_as_float(r0.y));
      GATHER_FMA(r1.x, __int_as_float(r1.y));
    }
    for (; i < nb; i += 4) {
      int2 r0 = sdst[o + i + q];
      GATHER_FMA(r0.x, __int_as_float(r0.y));
    }
#undef GATHER_FMA

    // reduce across the 4 vote-quarters
#pragma unroll
    for (int k = 0; k < 8; ++k) {
      float t = acc[k] + __shfl_xor(acc[k], 16);
      acc[k] = t + __shfl_xor(t, 32);
    }
    if (lane < 16) {
      int row = bin * 129 + (cg << 3);
#pragma unroll
      for (int k = 0; k < 8; ++k) lacc[row + k] = acc[k];
    }
  }
  __syncthreads();

  // overflow fold-in (empty in practice: one scalar load, skip)
  int cnt = *ofl_cnt;
  if (cnt > 0) {
    if (cnt > OFL_CAP) cnt = OFL_CAP;
    if (tid < 128) {
      for (int v = 0; v < cnt; ++v) {
        int2 rec = ofl[v];
        int h = rec.x >> 14;
        if (h >= ht0 && h < ht0 + RB) {
          int imv = rec.x & 0x3FFF;
          float wv = __int_as_float(rec.y);
          float xv = __uint_as_float(((unsigned int)xTh[((size_t)imv << 7) + tid]) << 16);
          lacc[(h - ht0) * 129 + tid] += wv * xv;  // same thread per ch -> no race
        }
      }
    }
    __syncthreads();
  }

  // transposed write-out: out[ch][ht0 + jj]; 8 lanes per ch -> 32 B runs
  int ch = tid >> 3;
  for (int jj = tid & 7; jj < RB; jj += 8)
    out[(size_t)ch * NHT + ht0 + jj] = lacc[jj * 129 + ch];
}

extern "C" void kernel_launch(void* const* d_in, const int* in_sizes, int n_in,
                              void* d_out, int out_size, void* d_ws, size_t ws_size,
                              hipStream_t stream) {
  const float* input_im = (const float*)d_in[0];
  const int*   im_idx   = (const int*)d_in[1];
  const int*   ht_idx   = (const int*)d_in[2];
  const float* weight   = (const float*)d_in[3];
  float*       out      = (float*)d_out;
  const int N = in_sizes[1];

  // workspace layout (~20.7 MB)
  char* w = (char*)d_ws;
  unsigned short* xTh = (unsigned short*)(w + 0);  //  4,194,304 B (HW*BC bf16)
  int2*  bkt     = (int2*) (w + 4194304);     // 16,392,192 B (NB*CAPB int2)
  int*   gcur    = (int*)  (w + 20586496);    //      2,208 B (NB i32)
  int*   ofl_cnt = (int*)  (w + 20588704);    //          4 B (contiguous w/ gcur)
  int2*  ofl     = (int2*) (w + 20589056);    //     65,536 B

  hipMemsetAsync(gcur, 0, 2212, stream);      // gcur + ofl_cnt in one memset
  k_work<<<NBK + NTR, 1024, 0, stream>>>(input_im, xTh, im_idx, ht_idx, weight, N,
                                         gcur, bkt, ofl_cnt, ofl);
  k_accum8<<<NB, 1024, 0, stream>>>(bkt, gcur, xTh, out, ofl_cnt, ofl);
}

// Round 13
// 129.118 us; speedup vs baseline: 1.0763x; 1.0763x over previous
//
#include <hip/hip_runtime.h>

// IM2HT Hough voting:
//   out[b,c,ht] = sum_{n: ht_idx[n]==ht} input_im[b,c,im_idx[n]] * weight[n]
// B*C = 128, HW = 16384, NHT = 184*180 = 33120, N = 1.5M votes.
//
// Pipeline (memset + 2 kernels):
//   0. hipMemsetAsync : zero bucket cursors + overflow counter (contiguous)
//   1. k_work   : blocks 0..366  -> bucket multi-split into 552 coarse ranges;
//                 records PACKED to 32 bits: hl(6) | wq(12) | im(14), weight
//                 quantized to 12-bit fixed point (err <= 1.2e-4)
//                 blocks 367..878 -> transpose in[BC][HW] -> xTh[HW][128] bf16
//   2. k_accum8 : one 1024-thr block per range (16 waves):
//                 hist pass reads records straight from L2 (no LDS staging),
//                 wave-0 scan, sort-scatter into LDS sdst (padded to x4),
//                 ALL 16 waves accumulate bins strided via quarter-wave bf16x8
//                 gathers (16-vote unroll = 4 gathers in flight), fused
//                 transposed write out[ch][r*60+j] (+ overflow fold-in)

#define HW   16384
#define BC   128
#define NHT  33120
#define RB   60            // ht bins per coarse range
#define NB   552           // NHT / RB
#define CAPB 3712          // bkt slots per range (mean 2717)
#define CAPR 3528          // raw record clamp, +15 sigma
#define CAPD 3712          // sorted slots (<= 3528 + 3*60 = 3708)
#define VPB  4096          // votes per bucket block
#define NBK  367           // bucket blocks = ceil(N / VPB)
#define NTR  512           // transpose blocks (4 tiles each = 2048 tiles)
#define OFL_CAP 8192

typedef int iv4 __attribute__((ext_vector_type(4)));

__device__ __forceinline__ unsigned short f2bf(float f) {
  unsigned int u = __float_as_uint(f);
  u = (u + 0x7fff + ((u >> 16) & 1)) >> 16;   // round-to-nearest-even
  return (unsigned short)u;
}

// blocks 0..NBK-1: bucket pass; blocks NBK..NBK+NTR-1: transpose pass
__global__ __launch_bounds__(1024) void k_work(
    const float* __restrict__ in, unsigned short* __restrict__ xTh,
    const int* __restrict__ im, const int* __restrict__ ht,
    const float* __restrict__ wt, int n,
    int* __restrict__ gcur, int* __restrict__ bkt,
    int* __restrict__ ofl_cnt, int2* __restrict__ ofl) {
  __shared__ __align__(16) char smem[4 * 32 * 33 * 4];  // 16,896 B union
  int tid = threadIdx.x;

  if (blockIdx.x >= NBK) {
    // ---- transpose: 4 independent 32x32 tiles per block ----
    float* tilef = (float*)smem;
    int sub = tid >> 8;                  // 0..3
    int t256 = tid & 255;
    int tx = t256 & 31, ty = t256 >> 5;  // 32 x 8
    int tileIdx = (blockIdx.x - NBK) * 4 + sub;
    int hw0 = (tileIdx & 511) * 32, bc0 = (tileIdx >> 9) * 32;
    float* tile = tilef + sub * (32 * 33);
#pragma unroll
    for (int k = 0; k < 32; k += 8)
      tile[(ty + k) * 33 + tx] = in[(size_t)(bc0 + ty + k) * HW + hw0 + tx];
    __syncthreads();
#pragma unroll
    for (int k = 0; k < 32; k += 8)
      xTh[(size_t)(hw0 + ty + k) * BC + bc0 + tx] = f2bf(tile[tx * 33 + ty + k]);
    return;
  }

  // ---- bucket multi-split (int4-vectorized vote loads; N % 4 == 0) ----
  int* cnt = (int*)smem;          // [NB]
  int* base = cnt + NB;           // [NB]
  int i0 = blockIdx.x * VPB;
  for (int b = tid; b < NB; b += 1024) cnt[b] = 0;
  __syncthreads();
  int vbase = i0 + (tid << 2);
  bool valid = vbase < n;
  int4 h4 = {0, 0, 0, 0}, i4 = {0, 0, 0, 0};
  float4 w4 = {0, 0, 0, 0};
  if (valid) {
    h4 = *(const int4*)(ht + vbase);
    i4 = *(const int4*)(im + vbase);
    w4 = *(const float4*)(wt + vbase);
  }
  int hb[4] = {h4.x / RB, h4.y / RB, h4.z / RB, h4.w / RB};
  if (valid) {
    atomicAdd(&cnt[hb[0]], 1);
    atomicAdd(&cnt[hb[1]], 1);
    atomicAdd(&cnt[hb[2]], 1);
    atomicAdd(&cnt[hb[3]], 1);
  }
  __syncthreads();
  for (int b = tid; b < NB; b += 1024) {
    int c = cnt[b];
    base[b] = c ? atomicAdd(&gcur[b], c) : 0;  // reserve private chunk
    cnt[b] = 0;                                 // reuse as local cursor
  }
  __syncthreads();
  if (valid) {
    int hv[4] = {h4.x, h4.y, h4.z, h4.w};
    int iv[4] = {i4.x, i4.y, i4.z, i4.w};
    float wv[4] = {w4.x, w4.y, w4.z, w4.w};
#pragma unroll
    for (int k = 0; k < 4; ++k) {
      int b = hb[k];
      int hl = hv[k] - b * RB;
      int wq = (int)(wv[k] * 4095.f + 0.5f);
      int pos = base[b] + atomicAdd(&cnt[b], 1);
      if (pos < CAPR) {
        bkt[(size_t)b * CAPB + pos] =
            (iv[k] & 0x3FFF) | (wq << 14) | (hl << 26);
      } else {
        int o = atomicAdd(ofl_cnt, 1);
        if (o < OFL_CAP)
          ofl[o] = make_int2((iv[k] & 0x3FFF) | (hv[k] << 14), __float_as_int(wv[k]));
      }
    }
  }
}

// one block per range: global-read hist + LDS counting sort + gather accumulate
__global__ __launch_bounds__(1024) void k_accum8(
    const int* __restrict__ bkt, const int* __restrict__ gcur,
    const unsigned short* __restrict__ xTh, float* __restrict__ out,
    const int* __restrict__ ofl_cnt, const int2* __restrict__ ofl) {
  __shared__ int sdst[CAPD];                   // 14,848 B sorted packed records
  __shared__ float lacc[RB * 129];             // 30,960 B accumulator
  __shared__ int hist[RB], off[RB], pcnt[RB], cur[RB];
  int tid = threadIdx.x;
  int r = blockIdx.x;
  int ht0 = r * RB;
  int n = gcur[r];
  if (n > CAPR) n = CAPR;
  const int* s = bkt + (size_t)r * CAPB;
  if (tid < RB) hist[tid] = 0;
  __syncthreads();
  for (int i = tid; i < n; i += 1024)          // hist pass: straight from L2
    atomicAdd(&hist[(unsigned)s[i] >> 26], 1);
  __syncthreads();
  if (tid < 64) {                              // wave-0 shfl inclusive scan
    int v = (tid < RB) ? ((hist[tid] + 3) & ~3) : 0;
    int inc = v;
#pragma unroll
    for (int d = 1; d < 64; d <<= 1) {
      int t = __shfl_up(inc, d);
      if (tid >= d) inc += t;
    }
    if (tid < RB) { off[tid] = inc - v; pcnt[tid] = v; cur[tid] = 0; }
  }
  __syncthreads();
  if (tid < RB) {                              // weight-0 dummies in pad slots
    for (int d = hist[tid]; d < pcnt[tid]; ++d)
      sdst[off[tid] + d] = 0;
  }
  for (int i = tid; i < n; i += 1024) {        // scatter into sorted order
    int v = s[i];
    int hl = (unsigned)v >> 26;
    int pos = off[hl] + atomicAdd(&cur[hl], 1);
    sdst[pos] = v & 0x03FFFFFF;                // strip hl, keep wq|im
  }
  __syncthreads();

  // accumulate: ALL 16 waves, bins strided; lane = (quarter q, octet cg)
  int w = __builtin_amdgcn_readfirstlane(tid >> 6);
  int lane = tid & 63;
  int q = lane >> 4;
  int cg = lane & 15;
  const unsigned short* xb = xTh + (cg << 3);
  for (int bin = w; bin < RB; bin += 16) {
    int o = off[bin], nb = pcnt[bin];          // nb % 4 == 0
    float acc[8] = {0, 0, 0, 0, 0, 0, 0, 0};

#define GATHER_FMA(R)                                                         \
  {                                                                           \
    int im_ = (R) & 0x3FFF;                                                   \
    float w_ = (float)(((R) >> 14) & 0xFFF) * (1.f / 4095.f);                 \
    iv4 xd = *(const iv4*)(xb + ((size_t)im_ << 7));                          \
    _Pragma("unroll") for (int c = 0; c < 4; ++c) {                           \
      float lo = __uint_as_float(((unsigned int)xd[c]) << 16);                \
      float hi = __uint_as_float(((unsigned int)xd[c]) & 0xffff0000u);        \
      acc[2 * c]     = fmaf(w_, lo, acc[2 * c]);                              \
      acc[2 * c + 1] = fmaf(w_, hi, acc[2 * c + 1]);                          \
    }                                                                         \
  }

    int i = 0;
    for (; i + 16 <= nb; i += 16) {            // 16 votes: 4 ds_reads + 4 gathers in flight
      int r0 = sdst[o + i + q];
      int r1 = sdst[o + i + 4 + q];
      int r2 = sdst[o + i + 8 + q];
      int r3 = sdst[o + i + 12 + q];
      GATHER_FMA(r0);
      GATHER_FMA(r1);
      GATHER_FMA(r2);
      GATHER_FMA(r3);
    }
    for (; i < nb; i += 4) {
      int r0 = sdst[o + i + q];
      GATHER_FMA(r0);
    }
#undef GATHER_FMA

    // reduce across the 4 vote-quarters
#pragma unroll
    for (int k = 0; k < 8; ++k) {
      float t = acc[k] + __shfl_xor(acc[k], 16);
      acc[k] = t + __shfl_xor(t, 32);
    }
    if (lane < 16) {
      int row = bin * 129 + (cg << 3);
#pragma unroll
      for (int k = 0; k < 8; ++k) lacc[row + k] = acc[k];
    }
  }
  __syncthreads();

  // overflow fold-in (empty in practice: one scalar load, skip)
  int cnt = *ofl_cnt;
  if (cnt > 0) {
    if (cnt > OFL_CAP) cnt = OFL_CAP;
    if (tid < 128) {
      for (int v = 0; v < cnt; ++v) {
        int2 rec = ofl[v];
        int h = rec.x >> 14;
        if (h >= ht0 && h < ht0 + RB) {
          int imv = rec.x & 0x3FFF;
          float wv = __int_as_float(rec.y);
          float xv = __uint_as_float(((unsigned int)xTh[((size_t)imv << 7) + tid]) << 16);
          lacc[(h - ht0) * 129 + tid] += wv * xv;  // same thread per ch -> no race
        }
      }
    }
    __syncthreads();
  }

  // transposed write-out: out[ch][ht0 + jj]; 8 lanes per ch -> 32 B runs
  int ch = tid >> 3;
  for (int jj = tid & 7; jj < RB; jj += 8)
    out[(size_t)ch * NHT + ht0 + jj] = lacc[jj * 129 + ch];
}

extern "C" void kernel_launch(void* const* d_in, const int* in_sizes, int n_in,
                              void* d_out, int out_size, void* d_ws, size_t ws_size,
                              hipStream_t stream) {
  const float* input_im = (const float*)d_in[0];
  const int*   im_idx   = (const int*)d_in[1];
  const int*   ht_idx   = (const int*)d_in[2];
  const float* weight   = (const float*)d_in[3];
  float*       out      = (float*)d_out;
  const int N = in_sizes[1];

  // workspace layout (~12.5 MB)
  char* w = (char*)d_ws;
  unsigned short* xTh = (unsigned short*)(w + 0);  //  4,194,304 B (HW*BC bf16)
  int*   bkt     = (int*)  (w + 4194304);     //  8,196,096 B (NB*CAPB i32)
  int*   gcur    = (int*)  (w + 12390400);    //      2,208 B (NB i32)
  int*   ofl_cnt = (int*)  (w + 12392608);    //          4 B (contiguous w/ gcur)
  int2*  ofl     = (int2*) (w + 12392960);    //     65,536 B

  hipMemsetAsync(gcur, 0, 2212, stream);      // gcur + ofl_cnt in one memset
  k_work<<<NBK + NTR, 1024, 0, stream>>>(input_im, xTh, im_idx, ht_idx, weight, N,
                                         gcur, bkt, ofl_cnt, ofl);
  k_accum8<<<NB, 1024, 0, stream>>>(bkt, gcur, xTh, out, ofl_cnt, ofl);
}